// Round 2
// baseline (350.922 us; speedup 1.0000x reference)
//
#include <hip/hip_runtime.h>

#define IMG_H 512
#define IMG_W 512

typedef _Float16 h2 __attribute__((ext_vector_type(2)));

__device__ __forceinline__ void ce(h2& a, h2& b) {
    h2 lo = __builtin_elementwise_min(a, b);  // v_pk_min_f16
    h2 hi = __builtin_elementwise_max(a, b);  // v_pk_max_f16
    a = lo;
    b = hi;
}

// Each thread computes the 7x7 median for TWO pixels: (y, xA) and (y, xA+64).
// The two pixels ride in the low/high halves of packed-f16 registers, so every
// compare-exchange (v_pk_min_f16 + v_pk_max_f16) serves both pixels.
// f16 rounding is monotone, so the rank-24 order statistic of the rounded
// window equals the rounded true median (error <= 2.4e-4 on [0,1)).
__global__ __launch_bounds__(256) void median7x7_kernel(
        const float* __restrict__ img, float* __restrict__ out) {
    const int bc = blockIdx.z;                      // fused batch*channel, 24
    const int y  = blockIdx.y * 4 + threadIdx.y;    // 0..511
    const int xA = blockIdx.x * 128 + threadIdx.x;  // 0..511 (lane-coalesced)
    const int xB = xA + 64;

    const float* base = img + (size_t)bc * (IMG_H * IMG_W);

    // Precompute clamped column indices + validity masks (zero padding).
    int  xcA[7], xcB[7];
    bool mxA[7], mxB[7];
#pragma unroll
    for (int d = 0; d < 7; ++d) {
        int xa = xA + d - 3;
        mxA[d] = (unsigned)xa < IMG_W;
        xcA[d] = min(max(xa, 0), IMG_W - 1);
        int xb = xB + d - 3;
        mxB[d] = (unsigned)xb < IMG_W;
        xcB[d] = min(max(xb, 0), IMG_W - 1);
    }

    h2 v[49];
#pragma unroll
    for (int dy = 0; dy < 7; ++dy) {
        int yy = y + dy - 3;
        bool my = (unsigned)yy < IMG_H;
        const float* row = base + (size_t)min(max(yy, 0), IMG_H - 1) * IMG_W;
#pragma unroll
        for (int dx = 0; dx < 7; ++dx) {
            float fa = (my && mxA[dx]) ? row[xcA[dx]] : 0.0f;
            float fb = (my && mxB[dx]) ? row[xcB[dx]] : 0.0f;
            h2 t;
            t.x = (_Float16)fa;
            t.y = (_Float16)fb;
            v[dy * 7 + dx] = t;
        }
    }

    // Batcher odd-even mergesort for arbitrary n (Sedgewick). n = 49.
    // Fully unrolled: all indices are compile-time constants -> registers.
    constexpr int n = 49;
#pragma unroll
    for (int p = 1; p < n; p += p) {
#pragma unroll
        for (int k = p; k > 0; k /= 2) {
#pragma unroll
            for (int j = k % p; j + k < n; j += k + k) {
#pragma unroll
                for (int i = 0; i < k; ++i) {
                    if (i + j + k < n) {
                        if ((i + j) / (p + p) == (i + j + k) / (p + p)) {
                            ce(v[i + j], v[i + j + k]);
                        }
                    }
                }
            }
        }
    }

    size_t o = (size_t)bc * (IMG_H * IMG_W) + (size_t)y * IMG_W;
    out[o + xA] = (float)v[24].x;  // rank 24 (0-indexed) = lower median
    out[o + xB] = (float)v[24].y;
}

extern "C" void kernel_launch(void* const* d_in, const int* in_sizes, int n_in,
                              void* d_out, int out_size, void* d_ws, size_t ws_size,
                              hipStream_t stream) {
    const float* img = (const float*)d_in[0];
    float* out = (float*)d_out;
    // 8*3=24 batch*channel planes; x tiled 128 wide (2 px/thread), y tiled 4.
    dim3 grid(IMG_W / 128, IMG_H / 4, 24);
    dim3 block(64, 4, 1);
    hipLaunchKernelGGL(median7x7_kernel, grid, block, 0, stream, img, out);
}

// Round 3
// 118.762 us; speedup vs baseline: 2.9548x; 2.9548x over previous
//
#include <hip/hip_runtime.h>

#define IMG_H 512
#define IMG_W 512

typedef _Float16 h2 __attribute__((ext_vector_type(2)));

__device__ __forceinline__ void ce(h2& a, h2& b) {
    h2 lo = __builtin_elementwise_min(a, b);  // v_pk_min_f16
    h2 hi = __builtin_elementwise_max(a, b);  // v_pk_max_f16
    a = lo;
    b = hi;
}

// ---------------------------------------------------------------------------
// Compile-time generation of a pruned Batcher odd-even merge network that
// takes 7 sorted columns of 7 (laid out in 8-slot runs, slot 8c+7 = virtual
// +inf pad) and produces the rank-24 element (the median of 49) in slot 24.
//   - stages p=8,16,32 of bottom-up odd-even mergesort (p<8 skipped: the
//     8-aligned runs are presorted -- columns sorted + pad on top)
//   - virtual pads tracked symbolically: CE with a pad input degenerates to
//     a no-op or a register move; pads are never materialized
//   - backward dependency pruning from output slot 24
// ---------------------------------------------------------------------------
struct Op { int kind, a, b; };  // 0: ce(v[a],v[b])  1: v[a]=v[b]  2: v[a]=cols[b]
constexpr int SLOTS = 56;
constexpr int MAXOPS = 600;
struct Net { Op ops[MAXOPS]; int n; bool ok; };

constexpr Net build_net() {
    Net net{};
    Op raw[MAXOPS] = {};
    int nraw = 0;
    bool pad[SLOTS] = {};
    // initial loads: slot 8c+r <- cols[c*7+r]; slot 8c+7 is a pad
    for (int c = 0; c < 7; ++c)
        for (int r = 0; r < 8; ++r) {
            int s = c * 8 + r;
            if (r < 7) raw[nraw++] = Op{2, s, c * 7 + r};
            else pad[s] = true;
        }
    // Batcher odd-even mergesort stages p = 8,16,32 on 56 slots
    for (int p = 8; p < SLOTS; p += p)
        for (int k = p; k > 0; k /= 2)
            for (int j = k % p; j + k < SLOTS; j += k + k)
                for (int i = 0; i < k; ++i) {
                    int a = i + j, b = i + j + k;
                    if (b < SLOTS && a / (p + p) == b / (p + p)) {
                        if (pad[a] && pad[b]) { /* skip */ }
                        else if (!pad[a] && pad[b]) { /* min stays, no-op */ }
                        else if (pad[a] && !pad[b]) {
                            raw[nraw++] = Op{1, a, b};  // value falls to a
                            pad[a] = false; pad[b] = true;
                        } else {
                            raw[nraw++] = Op{0, a, b};
                        }
                    }
                }
    net.ok = (!pad[24]) && (nraw < MAXOPS);
    // backward prune: keep only ops feeding slot 24
    bool needed[SLOTS] = {};
    needed[24] = true;
    bool keep[MAXOPS] = {};
    for (int t = nraw - 1; t >= 0; --t) {
        Op o = raw[t];
        if (o.kind == 0) {
            if (needed[o.a] || needed[o.b]) { keep[t] = true; needed[o.a] = true; needed[o.b] = true; }
        } else if (o.kind == 1) {
            if (needed[o.a]) { keep[t] = true; needed[o.a] = false; needed[o.b] = true; }
        } else {
            if (needed[o.a]) { keep[t] = true; needed[o.a] = false; }
        }
    }
    net.n = 0;
    for (int t = 0; t < nraw; ++t)
        if (keep[t]) net.ops[net.n++] = raw[t];
    return net;
}

constexpr Net NET = build_net();
static_assert(NET.ok, "median network generation failed");

template <int I>
__device__ __forceinline__ void run_net(h2* v, const h2* cols) {
    if constexpr (I < NET.n) {
        constexpr Op o = NET.ops[I];
        if constexpr (o.kind == 0) ce(v[o.a], v[o.b]);
        else if constexpr (o.kind == 1) v[o.a] = v[o.b];
        else v[o.a] = cols[o.b];
        run_net<I + 1>(v, cols);
    }
}

// Each thread: 4 (horizontal) x 2 (vertical, packed in f16 halves) output
// pixels. Loads 8 rows x 12 cols as 3 float4 per row; sorts the 10 shared
// packed columns once; runs the pruned merge network 4x.
__global__ __launch_bounds__(256) void median7x7_kernel(
        const float* __restrict__ img, float* __restrict__ out) {
    const int bc = blockIdx.z;
    const int tx = threadIdx.x;                       // 0..63
    const int ty = threadIdx.y;                       // 0..3
    const int x0 = (blockIdx.x * 64 + tx) * 4;        // 0..508, step 4
    const int y  = (blockIdx.y * 4 + ty) * 2;         // 0..510, step 2

    const float* base = img + (size_t)bc * (IMG_H * IMG_W);

    const bool okl = (x0 >= 4);
    const bool okr = (x0 <= 504);
    const int xl = okl ? (x0 - 4) : 0;
    const int xr = okr ? (x0 + 4) : 504;

    h2 col[10][7];
#pragma unroll
    for (int r = 0; r < 8; ++r) {
        const int yy = y - 3 + r;
        float4 L, M, R;
        if ((unsigned)yy < IMG_H) {  // wave-uniform: blockDim.x == 64
            const float* rp = base + (size_t)yy * IMG_W;
            L = *(const float4*)(rp + xl);
            M = *(const float4*)(rp + x0);
            R = *(const float4*)(rp + xr);
        } else {
            L = make_float4(0.f, 0.f, 0.f, 0.f);
            M = L;
            R = L;
        }
        float w[12];
        w[0] = 0.f;              w[1] = okl ? L.y : 0.f;
        w[2] = okl ? L.z : 0.f;  w[3] = okl ? L.w : 0.f;
        w[4] = M.x; w[5] = M.y; w[6] = M.z; w[7] = M.w;
        w[8] = okr ? R.x : 0.f;  w[9] = okr ? R.y : 0.f;
        w[10] = okr ? R.z : 0.f; w[11] = 0.f;
#pragma unroll
        for (int c = 0; c < 10; ++c) {
            _Float16 h = (_Float16)w[c + 1];
            if (r >= 1) col[c][r - 1].y = h;  // serves pixel row y+1
            if (r <= 6) col[c][r].x = h;      // serves pixel row y
        }
    }

    // sort each packed column of 7 (Batcher, same proven construction)
#pragma unroll
    for (int c = 0; c < 10; ++c) {
        h2* a = col[c];
#pragma unroll
        for (int p = 1; p < 7; p += p)
#pragma unroll
            for (int k = p; k > 0; k /= 2)
#pragma unroll
                for (int j = k % p; j + k < 7; j += k + k)
#pragma unroll
                    for (int i = 0; i < k; ++i)
                        if (i + j + k < 7)
                            if ((i + j) / (p + p) == (i + j + k) / (p + p))
                                ce(a[i + j], a[i + j + k]);
    }

    float o0[4], o1[4];
#pragma unroll
    for (int d = 0; d < 4; ++d) {
        h2 v[SLOTS];
        run_net<0>(v, &col[d][0]);
        o0[d] = (float)v[24].x;
        o1[d] = (float)v[24].y;
    }

    float* op = out + (size_t)bc * (IMG_H * IMG_W) + (size_t)y * IMG_W + x0;
    *(float4*)op = make_float4(o0[0], o0[1], o0[2], o0[3]);
    *(float4*)(op + IMG_W) = make_float4(o1[0], o1[1], o1[2], o1[3]);
}

extern "C" void kernel_launch(void* const* d_in, const int* in_sizes, int n_in,
                              void* d_out, int out_size, void* d_ws, size_t ws_size,
                              hipStream_t stream) {
    const float* img = (const float*)d_in[0];
    float* out = (float*)d_out;
    // x: 2 blocks * 64 threads * 4 px; y: 64 blocks * 4 threads * 2 rows; z: B*C
    dim3 grid(2, 64, 24);
    dim3 block(64, 4, 1);
    hipLaunchKernelGGL(median7x7_kernel, grid, block, 0, stream, img, out);
}

// Round 4
// 98.662 us; speedup vs baseline: 3.5568x; 1.2037x over previous
//
#include <hip/hip_runtime.h>
#include <utility>

#define IMG_H 512
#define IMG_W 512

typedef _Float16 h2 __attribute__((ext_vector_type(2)));

__device__ __forceinline__ h2 h2min(h2 a, h2 b) { return __builtin_elementwise_min(a, b); }
__device__ __forceinline__ h2 h2max(h2 a, h2 b) { return __builtin_elementwise_max(a, b); }

// ---------------------------------------------------------------------------
// Compile-time linear program over virtual register slots.
// kinds: 0 ce(a,b)            1 mov v[a]=v[b]      2 load v[a]=cols[b]
//        3 store med[a]=v[b]  4 v[a]=min(a,b)      5 v[b]=max(a,b)
// Virtual +inf pads are tracked symbolically at build time (a CE against a
// pad degenerates to a no-op or a move). After building, a backward pass
// prunes every op not feeding the 4 outputs, and one-sided CEs degrade to
// single min/max ops. Machinery (Batcher arbitrary-n sort + pow2 odd-even
// merge stage + pad tracking + pruning) is the round-3-validated code,
// generalized.
// ---------------------------------------------------------------------------
struct Op { int kind, a, b; };
constexpr int NSLOT = 320;
constexpr int MAXOPS = 4096;
struct Prog { Op ops[MAXOPS]; int n; bool ok; };

constexpr int pow2ceil(int x) { int p = 1; while (p < x) p += p; return p; }

struct Builder {
    Op ops[MAXOPS] = {};
    int n = 0;
    bool pad[NSLOT] = {};
    bool init[NSLOT] = {};
    bool ok = true;

    constexpr void emit(int k, int a, int b) {
        if (n < MAXOPS) ops[n++] = Op{k, a, b}; else ok = false;
    }
    constexpr void load(int s, int c) { emit(2, s, c); pad[s] = false; init[s] = true; }
    constexpr void mov(int d, int s) {
        if (!init[s]) ok = false;
        emit(1, d, s); pad[d] = pad[s]; init[d] = true;
    }
    constexpr void mkpad(int s) { pad[s] = true; init[s] = true; }
    constexpr void ce_(int a, int b) {
        if (!init[a] || !init[b]) { ok = false; return; }
        if (pad[a] && pad[b]) return;
        if (!pad[a] && pad[b]) return;                      // min stays low: no-op
        if (pad[a] && !pad[b]) {                            // value falls to a
            emit(1, a, b); pad[a] = false; pad[b] = true; return;
        }
        emit(0, a, b);
    }
    // Batcher odd-even mergesort, arbitrary n (round-2/3 validated form)
    constexpr void sort_run(int base, int len) {
        for (int p = 1; p < len; p += p)
            for (int k = p; k > 0; k /= 2)
                for (int j = k % p; j + k < len; j += k + k)
                    for (int i = 0; i < k; ++i)
                        if (i + j + k < len)
                            if ((i + j) / (p + p) == (i + j + k) / (p + p))
                                ce_(base + i + j, base + i + j + k);
    }
    // merge two sorted P-runs at [base,base+P) and [base+P,base+2P)
    constexpr void merge_stage(int base, int P) {
        int nn = 2 * P, p = P;
        for (int k = p; k > 0; k /= 2)
            for (int j = k % p; j + k < nn; j += k + k)
                for (int i = 0; i < k; ++i) {
                    int a = i + j, b = i + j + k;
                    if (b < nn && a / (p + p) == b / (p + p)) ce_(base + a, base + b);
                }
    }
    constexpr void load_col(int base, int c) {  // packed col c, sorted, at base..base+7
        for (int r = 0; r < 7; ++r) load(base + r, c * 7 + r);
        sort_run(base, 7);
    }
    constexpr void place(int dst, int src, int len, int P) {
        for (int i = 0; i < len; ++i) mov(dst + i, src + i);
        for (int i = len; i < P; ++i) mkpad(dst + i);
    }
    // merge sorted runs (s1,l1),(s2,l2) into fresh frame at dst (2P slots);
    // result: sorted l1+l2 at [dst, dst+l1+l2)
    constexpr void merge_to(int dst, int s1, int l1, int s2, int l2) {
        int P = pow2ceil(l1 > l2 ? l1 : l2);
        place(dst, s1, l1, P);
        place(dst + P, s2, l2, P);
        merge_stage(dst, P);
    }
    constexpr void outop(int o, int slot) {
        if (!init[slot] || pad[slot]) ok = false;
        emit(3, o, slot);
    }
};

constexpr Prog build() {
    Builder b{};
    constexpr int F34 = 0, F56 = 32, FC = 64, FP12 = 128, FP78 = 160;
    constexpr int C0 = 192, C9 = 200, C2c = 208, C7c = 216, FT = 224, FF = 256;

    // ---- shared work ----
    b.load_col(F34, 3); b.mkpad(F34 + 7); b.load_col(F34 + 8, 4); b.mkpad(F34 + 15);
    b.merge_stage(F34, 8);                           // sorted14(3,4) @F34
    b.load_col(F56, 5); b.mkpad(F56 + 7); b.load_col(F56 + 8, 6); b.mkpad(F56 + 15);
    b.merge_stage(F56, 8);                           // sorted14(5,6) @F56
    b.merge_to(FC, F34, 14, F56, 14);                // C28 = sorted(3..6) @FC

    b.load_col(FP12, 1); b.mkpad(FP12 + 7);
    b.load_col(FP12 + 8, 2);
    for (int i = 0; i < 7; ++i) b.mov(C2c + i, FP12 + 8 + i);  // keep sorted col2
    b.mkpad(FP12 + 15); b.merge_stage(FP12, 8);      // P12 = sorted14(1,2)

    b.load_col(FP78, 7);
    for (int i = 0; i < 7; ++i) b.mov(C7c + i, FP78 + i);      // keep sorted col7
    b.mkpad(FP78 + 7); b.load_col(FP78 + 8, 8); b.mkpad(FP78 + 15);
    b.merge_stage(FP78, 8);                          // P78 = sorted14(7,8)

    b.load_col(C0, 0); b.load_col(C9, 9);

    // ---- per-output: merge {C28} + {14-run} + {col} and take rank 24 ----
    b.merge_to(FT, FP12, 14, C0, 7);  b.merge_to(FF, FC, 28, FT, 21); b.outop(0, FF + 24);
    b.merge_to(FT, FP12, 14, C7c, 7); b.merge_to(FF, FC, 28, FT, 21); b.outop(1, FF + 24);
    b.merge_to(FT, FP78, 14, C2c, 7); b.merge_to(FF, FC, 28, FT, 21); b.outop(2, FF + 24);
    b.merge_to(FT, FP78, 14, C9, 7);  b.merge_to(FF, FC, 28, FT, 21); b.outop(3, FF + 24);

    // ---- backward prune + min/max degradation ----
    Prog p{};
    bool needed[NSLOT] = {};
    int kindr[MAXOPS] = {};
    bool keep[MAXOPS] = {};
    for (int t = b.n - 1; t >= 0; --t) {
        Op o = b.ops[t];
        if (o.kind == 3) { keep[t] = true; kindr[t] = 3; needed[o.b] = true; }
        else if (o.kind == 0) {
            bool na = needed[o.a], nb = needed[o.b];
            if (na && nb)      { keep[t] = true; kindr[t] = 0; }
            else if (na)       { keep[t] = true; kindr[t] = 4; needed[o.b] = true; }
            else if (nb)       { keep[t] = true; kindr[t] = 5; needed[o.a] = true; }
        } else if (o.kind == 1) {
            if (needed[o.a]) { keep[t] = true; kindr[t] = 1; needed[o.a] = false; needed[o.b] = true; }
        } else if (o.kind == 2) {
            if (needed[o.a]) { keep[t] = true; kindr[t] = 2; needed[o.a] = false; }
        }
    }
    p.n = 0;
    for (int t = 0; t < b.n; ++t)
        if (keep[t]) { p.ops[p.n] = b.ops[t]; p.ops[p.n].kind = kindr[t]; ++p.n; }
    p.ok = b.ok;
    return p;
}

constexpr Prog PROG = build();
static_assert(PROG.ok && PROG.n > 0 && PROG.n < MAXOPS, "program build failed");

template <int I>
__device__ __forceinline__ void step(h2* v, const h2* cols, h2* med) {
    constexpr Op o = PROG.ops[I];
    if constexpr (o.kind == 0) {
        h2 lo = h2min(v[o.a], v[o.b]);
        h2 hi = h2max(v[o.a], v[o.b]);
        v[o.a] = lo; v[o.b] = hi;
    } else if constexpr (o.kind == 1) v[o.a] = v[o.b];
    else if constexpr (o.kind == 2) v[o.a] = cols[o.b];
    else if constexpr (o.kind == 3) med[o.a] = v[o.b];
    else if constexpr (o.kind == 4) v[o.a] = h2min(v[o.a], v[o.b]);
    else v[o.b] = h2max(v[o.a], v[o.b]);
}

template <size_t... Is>
__device__ __forceinline__ void run_all(h2* v, const h2* cols, h2* med,
                                        std::index_sequence<Is...>) {
    (step<(int)Is>(v, cols, med), ...);
}

// Each thread: 4 (horizontal) x 2 (vertical, packed f16 halves) output pixels.
__global__ __launch_bounds__(256) void median7x7_kernel(
        const float* __restrict__ img, float* __restrict__ out) {
    const int bc = blockIdx.z;
    const int tx = threadIdx.x;                    // 0..63
    const int ty = threadIdx.y;                    // 0..3
    const int x0 = (blockIdx.x * 64 + tx) * 4;     // 0..508
    const int y  = (blockIdx.y * 4 + ty) * 2;      // 0..510

    const float* base = img + (size_t)bc * (IMG_H * IMG_W);
    const bool okl = (x0 >= 4);
    const bool okr = (x0 <= 504);
    const int xl = okl ? (x0 - 4) : 0;
    const int xr = okr ? (x0 + 4) : 504;

    // Packed columns: colv[c*7+d] = (img[y-3+d][xc], img[y-2+d][xc]), c=0..9.
    h2 colv[70];
    float prv[10];
#pragma unroll
    for (int r = 0; r < 8; ++r) {
        const int yy = y - 3 + r;
        float4 L, M, R;
        if ((unsigned)yy < IMG_H) {   // wave-uniform (blockDim.x == 64)
            const float* rp = base + (size_t)yy * IMG_W;
            L = *(const float4*)(rp + xl);
            M = *(const float4*)(rp + x0);
            R = *(const float4*)(rp + xr);
        } else {
            L = make_float4(0.f, 0.f, 0.f, 0.f); M = L; R = L;
        }
        float cur[10];
        cur[0] = okl ? L.y : 0.f; cur[1] = okl ? L.z : 0.f; cur[2] = okl ? L.w : 0.f;
        cur[3] = M.x; cur[4] = M.y; cur[5] = M.z; cur[6] = M.w;
        cur[7] = okr ? R.x : 0.f; cur[8] = okr ? R.y : 0.f; cur[9] = okr ? R.z : 0.f;
        if (r > 0) {
#pragma unroll
            for (int c = 0; c < 10; ++c)
                colv[c * 7 + (r - 1)] = (h2)__builtin_amdgcn_cvt_pkrtz(prv[c], cur[c]);
        }
#pragma unroll
        for (int c = 0; c < 10; ++c) prv[c] = cur[c];
    }

    h2 v[NSLOT];
    h2 med[4];
    run_all(v, colv, med, std::make_index_sequence<(size_t)PROG.n>{});

    float* op = out + (size_t)bc * (IMG_H * IMG_W) + (size_t)y * IMG_W + x0;
    *(float4*)op = make_float4((float)med[0].x, (float)med[1].x,
                               (float)med[2].x, (float)med[3].x);
    *(float4*)(op + IMG_W) = make_float4((float)med[0].y, (float)med[1].y,
                                         (float)med[2].y, (float)med[3].y);
}

extern "C" void kernel_launch(void* const* d_in, const int* in_sizes, int n_in,
                              void* d_out, int out_size, void* d_ws, size_t ws_size,
                              hipStream_t stream) {
    const float* img = (const float*)d_in[0];
    float* out = (float*)d_out;
    dim3 grid(2, 64, 24);
    dim3 block(64, 4, 1);
    hipLaunchKernelGGL(median7x7_kernel, grid, block, 0, stream, img, out);
}

// Round 5
// 94.124 us; speedup vs baseline: 3.7283x; 1.0482x over previous
//
#include <hip/hip_runtime.h>
#include <utility>

#define IMG_H 512
#define IMG_W 512

typedef _Float16 h2 __attribute__((ext_vector_type(2)));

__device__ __forceinline__ h2 h2min(h2 a, h2 b) { return __builtin_elementwise_min(a, b); }
__device__ __forceinline__ h2 h2max(h2 a, h2 b) { return __builtin_elementwise_max(a, b); }

// ---------------------------------------------------------------------------
// Compile-time linear program over virtual register slots (round-3/4
// validated machinery: Batcher sort/merge with symbolic +inf pads, backward
// pruning with min/max degradation). New this round:
//   - rank-selection identity: rank-r of A∪B (both sorted) =
//       min_{i+j=r+1} max(A[i-1], B[j-1])
//     applied at the last level (A = sorted-42, B = sorted column-7):
//     7 max + 7 min + 1 mov per output instead of a pruned 64-slot merge.
//   - output pairs share their sorted-42 run (C28 ∪ pair-of-columns).
// kinds: 0 ce(a,b)  1 mov v[a]=v[b]  2 load v[a]=cols[b]  3 store med[a]=v[b]
//        4 v[a]=min(v[a],v[b])       5 v[b]=max(v[a],v[b])
// ---------------------------------------------------------------------------
struct Op { int kind, a, b; };
constexpr int NSLOT = 320;
constexpr int MAXOPS = 4096;
struct Prog { Op ops[MAXOPS]; int n; bool ok; };

constexpr int pow2ceil(int x) { int p = 1; while (p < x) p += p; return p; }

struct Builder {
    Op ops[MAXOPS] = {};
    int n = 0;
    bool pad[NSLOT] = {};
    bool init[NSLOT] = {};
    bool ok = true;

    constexpr void emit(int k, int a, int b) {
        if (n < MAXOPS) ops[n++] = Op{k, a, b}; else ok = false;
    }
    constexpr void load(int s, int c) { emit(2, s, c); pad[s] = false; init[s] = true; }
    constexpr void mov(int d, int s) {
        if (!init[s]) ok = false;
        emit(1, d, s); pad[d] = pad[s]; init[d] = true;
    }
    constexpr void mkpad(int s) { pad[s] = true; init[s] = true; }
    constexpr void ce_(int a, int b) {
        if (!init[a] || !init[b]) { ok = false; return; }
        if (pad[a] && pad[b]) return;
        if (!pad[a] && pad[b]) return;                      // min stays low: no-op
        if (pad[a] && !pad[b]) {                            // value falls to a
            emit(1, a, b); pad[a] = false; pad[b] = true; return;
        }
        emit(0, a, b);
    }
    constexpr void maxin(int a, int b) {  // v[b] = max(v[a], v[b])
        if (!init[a] || !init[b] || pad[a] || pad[b]) ok = false;
        emit(5, a, b);
    }
    constexpr void minin(int a, int b) {  // v[a] = min(v[a], v[b])
        if (!init[a] || !init[b] || pad[a] || pad[b]) ok = false;
        emit(4, a, b);
    }
    // Batcher odd-even mergesort, arbitrary n (round-2/3/4 validated form)
    constexpr void sort_run(int base, int len) {
        for (int p = 1; p < len; p += p)
            for (int k = p; k > 0; k /= 2)
                for (int j = k % p; j + k < len; j += k + k)
                    for (int i = 0; i < k; ++i)
                        if (i + j + k < len)
                            if ((i + j) / (p + p) == (i + j + k) / (p + p))
                                ce_(base + i + j, base + i + j + k);
    }
    // merge two sorted P-runs at [base,base+P) and [base+P,base+2P)
    constexpr void merge_stage(int base, int P) {
        int nn = 2 * P, p = P;
        for (int k = p; k > 0; k /= 2)
            for (int j = k % p; j + k < nn; j += k + k)
                for (int i = 0; i < k; ++i) {
                    int a = i + j, b = i + j + k;
                    if (b < nn && a / (p + p) == b / (p + p)) ce_(base + a, base + b);
                }
    }
    constexpr void load_col(int base, int c) {  // packed col c, sorted, at base..base+6
        for (int r = 0; r < 7; ++r) load(base + r, c * 7 + r);
        sort_run(base, 7);
    }
    constexpr void place(int dst, int src, int len, int P) {
        for (int i = 0; i < len; ++i) mov(dst + i, src + i);
        for (int i = len; i < P; ++i) mkpad(dst + i);
    }
    // merge sorted runs (s1,l1),(s2,l2) into frame dst (2P slots); sources intact
    constexpr void merge_to(int dst, int s1, int l1, int s2, int l2) {
        int P = pow2ceil(l1 > l2 ? l1 : l2);
        place(dst, s1, l1, P);
        place(dst + P, s2, l2, P);
        merge_stage(dst, P);
    }
    // rank-24 (median of 49) of sorted-42 at A ∪ sorted-7 at B, via the
    // min-of-max identity; splits i∈[18,25]. T = 8 scratch slots.
    constexpr void select_med49(int T, int A, int B, int o) {
        for (int t = 0; t < 7; ++t) {
            mov(T + t, A + 17 + t);     // A[17+t]
            maxin(B + 6 - t, T + t);    // T+t = max(A[17+t], B[6-t])
        }
        mov(T + 7, A + 24);             // i=25 candidate (B prefix empty)
        minin(T, T + 1); minin(T + 2, T + 3);
        minin(T + 4, T + 5); minin(T + 6, T + 7);
        minin(T, T + 2); minin(T + 4, T + 6);
        minin(T, T + 4);
        if (!init[T] || pad[T]) ok = false;
        emit(3, o, T);
    }
};

constexpr Prog build() {
    Builder b{};
    // sorted column frames S[c] = 8c (c=0..9), then merge frames
    constexpr int F34 = 80, F56 = 112, FC = 144, FP12 = 176, FP78 = 208;
    constexpr int C42 = 240;  // 64-slot frame, reused for A then B
    constexpr int T0 = 304, T1 = 312;

    for (int c = 0; c < 10; ++c) b.load_col(8 * c, c);

    b.merge_to(F34, 8 * 3, 7, 8 * 4, 7);        // sorted14(3,4)
    b.merge_to(F56, 8 * 5, 7, 8 * 6, 7);        // sorted14(5,6)
    b.merge_to(FC, F34, 14, F56, 14);           // C28 = sorted(cols 3..6)

    b.merge_to(FP12, 8 * 1, 7, 8 * 2, 7);       // P12 = sorted14(1,2)
    b.merge_to(C42, FC, 28, FP12, 14);          // C42A = sorted42(cols 1..6)
    b.select_med49(T0, C42, 8 * 0, 0);          // out0: cols 0..6
    b.select_med49(T1, C42, 8 * 7, 1);          // out1: cols 1..7

    b.merge_to(FP78, 8 * 7, 7, 8 * 8, 7);       // P78 = sorted14(7,8)
    b.merge_to(C42, FC, 28, FP78, 14);          // C42B = sorted42(cols 3..8)
    b.select_med49(T0, C42, 8 * 2, 2);          // out2: cols 2..8
    b.select_med49(T1, C42, 8 * 9, 3);          // out3: cols 3..9

    // ---- backward prune + min/max degradation ----
    Prog p{};
    bool needed[NSLOT] = {};
    int kindr[MAXOPS] = {};
    bool keep[MAXOPS] = {};
    for (int t = b.n - 1; t >= 0; --t) {
        Op o = b.ops[t];
        if (o.kind == 3) { keep[t] = true; kindr[t] = 3; needed[o.b] = true; }
        else if (o.kind == 0) {
            bool na = needed[o.a], nb = needed[o.b];
            if (na && nb)      { keep[t] = true; kindr[t] = 0; }
            else if (na)       { keep[t] = true; kindr[t] = 4; needed[o.b] = true; }
            else if (nb)       { keep[t] = true; kindr[t] = 5; needed[o.a] = true; }
        } else if (o.kind == 1) {
            if (needed[o.a]) { keep[t] = true; kindr[t] = 1; needed[o.a] = false; needed[o.b] = true; }
        } else if (o.kind == 2) {
            if (needed[o.a]) { keep[t] = true; kindr[t] = 2; needed[o.a] = false; }
        } else if (o.kind == 4) {   // v[a]=min(a,b): reads a,b, writes a
            if (needed[o.a]) { keep[t] = true; kindr[t] = 4; needed[o.b] = true; }
        } else if (o.kind == 5) {   // v[b]=max(a,b): reads a,b, writes b
            if (needed[o.b]) { keep[t] = true; kindr[t] = 5; needed[o.a] = true; }
        }
    }
    p.n = 0;
    for (int t = 0; t < b.n; ++t)
        if (keep[t]) { p.ops[p.n] = b.ops[t]; p.ops[p.n].kind = kindr[t]; ++p.n; }
    p.ok = b.ok;
    return p;
}

constexpr Prog PROG = build();
static_assert(PROG.ok && PROG.n > 0 && PROG.n < MAXOPS, "program build failed");

template <int I>
__device__ __forceinline__ void step(h2* v, const h2* cols, h2* med) {
    constexpr Op o = PROG.ops[I];
    if constexpr (o.kind == 0) {
        h2 lo = h2min(v[o.a], v[o.b]);
        h2 hi = h2max(v[o.a], v[o.b]);
        v[o.a] = lo; v[o.b] = hi;
    } else if constexpr (o.kind == 1) v[o.a] = v[o.b];
    else if constexpr (o.kind == 2) v[o.a] = cols[o.b];
    else if constexpr (o.kind == 3) med[o.a] = v[o.b];
    else if constexpr (o.kind == 4) v[o.a] = h2min(v[o.a], v[o.b]);
    else v[o.b] = h2max(v[o.a], v[o.b]);
}

template <size_t... Is>
__device__ __forceinline__ void run_all(h2* v, const h2* cols, h2* med,
                                        std::index_sequence<Is...>) {
    (step<(int)Is>(v, cols, med), ...);
}

// Each thread: 4 (horizontal) x 2 (vertical, packed f16 halves) output pixels.
__global__ __launch_bounds__(256) void median7x7_kernel(
        const float* __restrict__ img, float* __restrict__ out) {
    const int bc = blockIdx.z;
    const int tx = threadIdx.x;                    // 0..63
    const int ty = threadIdx.y;                    // 0..3
    const int x0 = (blockIdx.x * 64 + tx) * 4;     // 0..508
    const int y  = (blockIdx.y * 4 + ty) * 2;      // 0..510

    const float* base = img + (size_t)bc * (IMG_H * IMG_W);
    const bool okl = (x0 >= 4);
    const bool okr = (x0 <= 504);
    const int xl = okl ? (x0 - 4) : 0;
    const int xr = okr ? (x0 + 4) : 504;

    // Packed columns: colv[c*7+d] = (img[y-3+d][xc], img[y-2+d][xc]), c=0..9.
    h2 colv[70];
    float prv[10];
#pragma unroll
    for (int r = 0; r < 8; ++r) {
        const int yy = y - 3 + r;
        float4 L, M, R;
        if ((unsigned)yy < IMG_H) {   // wave-uniform (blockDim.x == 64)
            const float* rp = base + (size_t)yy * IMG_W;
            L = *(const float4*)(rp + xl);
            M = *(const float4*)(rp + x0);
            R = *(const float4*)(rp + xr);
        } else {
            L = make_float4(0.f, 0.f, 0.f, 0.f); M = L; R = L;
        }
        float cur[10];
        cur[0] = okl ? L.y : 0.f; cur[1] = okl ? L.z : 0.f; cur[2] = okl ? L.w : 0.f;
        cur[3] = M.x; cur[4] = M.y; cur[5] = M.z; cur[6] = M.w;
        cur[7] = okr ? R.x : 0.f; cur[8] = okr ? R.y : 0.f; cur[9] = okr ? R.z : 0.f;
        if (r > 0) {
#pragma unroll
            for (int c = 0; c < 10; ++c)
                colv[c * 7 + (r - 1)] = (h2)__builtin_amdgcn_cvt_pkrtz(prv[c], cur[c]);
        }
#pragma unroll
        for (int c = 0; c < 10; ++c) prv[c] = cur[c];
    }

    h2 v[NSLOT];
    h2 med[4];
    run_all(v, colv, med, std::make_index_sequence<(size_t)PROG.n>{});

    float* op = out + (size_t)bc * (IMG_H * IMG_W) + (size_t)y * IMG_W + x0;
    *(float4*)op = make_float4((float)med[0].x, (float)med[1].x,
                               (float)med[2].x, (float)med[3].x);
    *(float4*)(op + IMG_W) = make_float4((float)med[0].y, (float)med[1].y,
                                         (float)med[2].y, (float)med[3].y);
}

extern "C" void kernel_launch(void* const* d_in, const int* in_sizes, int n_in,
                              void* d_out, int out_size, void* d_ws, size_t ws_size,
                              hipStream_t stream) {
    const float* img = (const float*)d_in[0];
    float* out = (float*)d_out;
    dim3 grid(2, 64, 24);
    dim3 block(64, 4, 1);
    hipLaunchKernelGGL(median7x7_kernel, grid, block, 0, stream, img, out);
}

// Round 6
// 88.685 us; speedup vs baseline: 3.9570x; 1.0613x over previous
//
#include <hip/hip_runtime.h>
#include <utility>

#define IMG_H 512
#define IMG_W 512

typedef _Float16 h2 __attribute__((ext_vector_type(2)));

__device__ __forceinline__ h2 h2min(h2 a, h2 b) { return __builtin_elementwise_min(a, b); }
__device__ __forceinline__ h2 h2max(h2 a, h2 b) { return __builtin_elementwise_max(a, b); }

// ---------------------------------------------------------------------------
// Compile-time linear program (round-3/4/5 validated machinery: Batcher
// sort/merge with symbolic +inf pads, backward pruning with min/max
// degradation, rank-selection identity for the final level).
// Round 6: 8-wide strip — two 4-wide groups sharing column sorts g0..g13
// and the 14-runs m(5,6), m(7,8) between their merge trees.
// kinds: 0 ce(a,b)  1 mov v[a]=v[b]  2 load v[a]=cols[b]  3 store med[a]=v[b]
//        4 v[a]=min(v[a],v[b])       5 v[b]=max(v[a],v[b])
// ---------------------------------------------------------------------------
struct Op { int kind, a, b; };
constexpr int NSLOT = 352;
constexpr int MAXOPS = 4096;
struct Prog { Op ops[MAXOPS]; int n; bool ok; };

constexpr int pow2ceil(int x) { int p = 1; while (p < x) p += p; return p; }

struct Builder {
    Op ops[MAXOPS] = {};
    int n = 0;
    bool pad[NSLOT] = {};
    bool init[NSLOT] = {};
    bool ok = true;

    constexpr void emit(int k, int a, int b) {
        if (n < MAXOPS) ops[n++] = Op{k, a, b}; else ok = false;
    }
    constexpr void load(int s, int c) { emit(2, s, c); pad[s] = false; init[s] = true; }
    constexpr void mov(int d, int s) {
        if (!init[s]) ok = false;
        emit(1, d, s); pad[d] = pad[s]; init[d] = true;
    }
    constexpr void mkpad(int s) { pad[s] = true; init[s] = true; }
    constexpr void ce_(int a, int b) {
        if (!init[a] || !init[b]) { ok = false; return; }
        if (pad[a] && pad[b]) return;
        if (!pad[a] && pad[b]) return;                      // min stays low: no-op
        if (pad[a] && !pad[b]) {                            // value falls to a
            emit(1, a, b); pad[a] = false; pad[b] = true; return;
        }
        emit(0, a, b);
    }
    constexpr void maxin(int a, int b) {  // v[b] = max(v[a], v[b])
        if (!init[a] || !init[b] || pad[a] || pad[b]) ok = false;
        emit(5, a, b);
    }
    constexpr void minin(int a, int b) {  // v[a] = min(v[a], v[b])
        if (!init[a] || !init[b] || pad[a] || pad[b]) ok = false;
        emit(4, a, b);
    }
    constexpr void sort_run(int base, int len) {
        for (int p = 1; p < len; p += p)
            for (int k = p; k > 0; k /= 2)
                for (int j = k % p; j + k < len; j += k + k)
                    for (int i = 0; i < k; ++i)
                        if (i + j + k < len)
                            if ((i + j) / (p + p) == (i + j + k) / (p + p))
                                ce_(base + i + j, base + i + j + k);
    }
    constexpr void merge_stage(int base, int P) {
        int nn = 2 * P, p = P;
        for (int k = p; k > 0; k /= 2)
            for (int j = k % p; j + k < nn; j += k + k)
                for (int i = 0; i < k; ++i) {
                    int a = i + j, b = i + j + k;
                    if (b < nn && a / (p + p) == b / (p + p)) ce_(base + a, base + b);
                }
    }
    constexpr void load_col(int base, int c) {  // packed col c, sorted
        for (int r = 0; r < 7; ++r) load(base + r, c * 7 + r);
        sort_run(base, 7);
    }
    constexpr void place(int dst, int src, int len, int P) {
        for (int i = 0; i < len; ++i) mov(dst + i, src + i);
        for (int i = len; i < P; ++i) mkpad(dst + i);
    }
    // merge sorted runs (s1,l1),(s2,l2) into frame dst (2P slots); sources intact
    constexpr void merge_to(int dst, int s1, int l1, int s2, int l2) {
        int P = pow2ceil(l1 > l2 ? l1 : l2);
        place(dst, s1, l1, P);
        place(dst + P, s2, l2, P);
        merge_stage(dst, P);
    }
    // rank-24 of sorted-42 at A ∪ sorted-7 at B (min-of-max identity)
    constexpr void select_med49(int T, int A, int B, int o) {
        for (int t = 0; t < 7; ++t) {
            mov(T + t, A + 17 + t);
            maxin(B + 6 - t, T + t);
        }
        mov(T + 7, A + 24);
        minin(T, T + 1); minin(T + 2, T + 3);
        minin(T + 4, T + 5); minin(T + 6, T + 7);
        minin(T, T + 2); minin(T + 4, T + 6);
        minin(T, T + 4);
        if (!init[T] || pad[T]) ok = false;
        emit(3, o, T);
    }
};

constexpr Prog build() {
    Builder b{};
    // sorted columns g_c at 8c (c=0..13); merge frames:
    constexpr int M12 = 112, M34 = 128, M56 = 144, M78 = 160, M910 = 176, M1112 = 192;
    constexpr int C28A = 208, C28B = 240, C42 = 272, T0 = 336, T1 = 344;

    // ---- group A (outputs 0..3, cols g0..g9) ----
    for (int c = 1; c <= 8; ++c) b.load_col(8 * c, c);
    b.merge_to(M34, 8 * 3, 7, 8 * 4, 7);
    b.merge_to(M56, 8 * 5, 7, 8 * 6, 7);          // shared with group B
    b.merge_to(C28A, M34, 14, M56, 14);           // sorted(g3..g6)
    b.merge_to(M12, 8 * 1, 7, 8 * 2, 7);
    b.merge_to(M78, 8 * 7, 7, 8 * 8, 7);          // shared with group B

    b.merge_to(C42, C28A, 28, M12, 14);           // sorted42(g1..g6)
    b.load_col(8 * 0, 0);
    b.select_med49(T0, C42, 8 * 0, 0);            // out0: g0..g6
    b.select_med49(T1, C42, 8 * 7, 1);            // out1: g1..g7

    b.merge_to(C42, C28A, 28, M78, 14);           // sorted42(g3..g8)
    b.load_col(8 * 9, 9);
    b.select_med49(T0, C42, 8 * 2, 2);            // out2: g2..g8
    b.select_med49(T1, C42, 8 * 9, 3);            // out3: g3..g9

    // ---- group B (outputs 4..7, cols g4..g13) ----
    b.load_col(8 * 10, 10);
    b.merge_to(M910, 8 * 9, 7, 8 * 10, 7);
    b.merge_to(C28B, M78, 14, M910, 14);          // sorted(g7..g10)

    b.merge_to(C42, C28B, 28, M56, 14);           // sorted42(g5..g10)
    b.select_med49(T0, C42, 8 * 4, 4);            // out4: g4..g10
    b.load_col(8 * 11, 11);
    b.select_med49(T1, C42, 8 * 11, 5);           // out5: g5..g11

    b.load_col(8 * 12, 12);
    b.merge_to(M1112, 8 * 11, 7, 8 * 12, 7);
    b.merge_to(C42, C28B, 28, M1112, 14);         // sorted42(g7..g12)
    b.select_med49(T0, C42, 8 * 6, 6);            // out6: g6..g12
    b.load_col(8 * 13, 13);
    b.select_med49(T1, C42, 8 * 13, 7);           // out7: g7..g13

    // ---- backward prune + min/max degradation ----
    Prog p{};
    bool needed[NSLOT] = {};
    int kindr[MAXOPS] = {};
    bool keep[MAXOPS] = {};
    for (int t = b.n - 1; t >= 0; --t) {
        Op o = b.ops[t];
        if (o.kind == 3) { keep[t] = true; kindr[t] = 3; needed[o.b] = true; }
        else if (o.kind == 0) {
            bool na = needed[o.a], nb = needed[o.b];
            if (na && nb)      { keep[t] = true; kindr[t] = 0; }
            else if (na)       { keep[t] = true; kindr[t] = 4; needed[o.b] = true; }
            else if (nb)       { keep[t] = true; kindr[t] = 5; needed[o.a] = true; }
        } else if (o.kind == 1) {
            if (needed[o.a]) { keep[t] = true; kindr[t] = 1; needed[o.a] = false; needed[o.b] = true; }
        } else if (o.kind == 2) {
            if (needed[o.a]) { keep[t] = true; kindr[t] = 2; needed[o.a] = false; }
        } else if (o.kind == 4) {
            if (needed[o.a]) { keep[t] = true; kindr[t] = 4; needed[o.b] = true; }
        } else if (o.kind == 5) {
            if (needed[o.b]) { keep[t] = true; kindr[t] = 5; needed[o.a] = true; }
        }
    }
    p.n = 0;
    for (int t = 0; t < b.n; ++t)
        if (keep[t]) { p.ops[p.n] = b.ops[t]; p.ops[p.n].kind = kindr[t]; ++p.n; }
    p.ok = b.ok;
    return p;
}

constexpr Prog PROG = build();
static_assert(PROG.ok && PROG.n > 0 && PROG.n < MAXOPS, "program build failed");

template <int I>
__device__ __forceinline__ void step(h2* v, const h2* cols, h2* med) {
    constexpr Op o = PROG.ops[I];
    if constexpr (o.kind == 0) {
        h2 lo = h2min(v[o.a], v[o.b]);
        h2 hi = h2max(v[o.a], v[o.b]);
        v[o.a] = lo; v[o.b] = hi;
    } else if constexpr (o.kind == 1) v[o.a] = v[o.b];
    else if constexpr (o.kind == 2) v[o.a] = cols[o.b];
    else if constexpr (o.kind == 3) med[o.a] = v[o.b];
    else if constexpr (o.kind == 4) v[o.a] = h2min(v[o.a], v[o.b]);
    else v[o.b] = h2max(v[o.a], v[o.b]);
}

template <size_t... Is>
__device__ __forceinline__ void run_all(h2* v, const h2* cols, h2* med,
                                        std::index_sequence<Is...>) {
    (step<(int)Is>(v, cols, med), ...);
}

// Each thread: 8 (horizontal) x 2 (vertical, packed f16 halves) output pixels.
__global__ __launch_bounds__(256) void median7x7_kernel(
        const float* __restrict__ img, float* __restrict__ out) {
    const int bc = blockIdx.z;
    const int tx = threadIdx.x;                    // 0..63
    const int ty = threadIdx.y;                    // 0..3
    const int x0 = (blockIdx.x * 64 + tx) * 8;     // 0..504
    const int y  = (blockIdx.y * 4 + ty) * 2;      // 0..510

    const float* base = img + (size_t)bc * (IMG_H * IMG_W);
    const bool okl = (x0 >= 4);          // false only for tx == 0
    const bool okr = (x0 <= 496);        // false only for tx == 63
    const int xl = okl ? (x0 - 4) : 0;
    const int xr = okr ? (x0 + 8) : 504;

    // Packed columns: colv[c*7+d] = (img[y-3+d][gc], img[y-2+d][gc]),
    // gc = x0-3+c, c = 0..13.
    h2 colv[98];
    float prv[14];
#pragma unroll
    for (int r = 0; r < 8; ++r) {
        const int yy = y - 3 + r;
        float4 Q0, Q1, Q2, Q3;
        if ((unsigned)yy < IMG_H) {   // wave-uniform (blockDim.x == 64)
            const float* rp = base + (size_t)yy * IMG_W;
            Q0 = *(const float4*)(rp + xl);
            Q1 = *(const float4*)(rp + x0);
            Q2 = *(const float4*)(rp + x0 + 4);
            Q3 = *(const float4*)(rp + xr);
        } else {
            Q0 = make_float4(0.f, 0.f, 0.f, 0.f); Q1 = Q0; Q2 = Q0; Q3 = Q0;
        }
        float cur[14];
        cur[0] = okl ? Q0.y : 0.f; cur[1] = okl ? Q0.z : 0.f; cur[2] = okl ? Q0.w : 0.f;
        cur[3] = Q1.x; cur[4] = Q1.y; cur[5] = Q1.z; cur[6] = Q1.w;
        cur[7] = Q2.x; cur[8] = Q2.y; cur[9] = Q2.z; cur[10] = Q2.w;
        cur[11] = okr ? Q3.x : 0.f; cur[12] = okr ? Q3.y : 0.f; cur[13] = okr ? Q3.z : 0.f;
        if (r > 0) {
#pragma unroll
            for (int c = 0; c < 14; ++c)
                colv[c * 7 + (r - 1)] = (h2)__builtin_amdgcn_cvt_pkrtz(prv[c], cur[c]);
        }
#pragma unroll
        for (int c = 0; c < 14; ++c) prv[c] = cur[c];
    }

    h2 v[NSLOT];
    h2 med[8];
    run_all(v, colv, med, std::make_index_sequence<(size_t)PROG.n>{});

    float* op = out + (size_t)bc * (IMG_H * IMG_W) + (size_t)y * IMG_W + x0;
    *(float4*)op = make_float4((float)med[0].x, (float)med[1].x,
                               (float)med[2].x, (float)med[3].x);
    *(float4*)(op + 4) = make_float4((float)med[4].x, (float)med[5].x,
                                     (float)med[6].x, (float)med[7].x);
    *(float4*)(op + IMG_W) = make_float4((float)med[0].y, (float)med[1].y,
                                         (float)med[2].y, (float)med[3].y);
    *(float4*)(op + IMG_W + 4) = make_float4((float)med[4].y, (float)med[5].y,
                                             (float)med[6].y, (float)med[7].y);
}

extern "C" void kernel_launch(void* const* d_in, const int* in_sizes, int n_in,
                              void* d_out, int out_size, void* d_ws, size_t ws_size,
                              hipStream_t stream) {
    const float* img = (const float*)d_in[0];
    float* out = (float*)d_out;
    dim3 grid(1, 64, 24);
    dim3 block(64, 4, 1);
    hipLaunchKernelGGL(median7x7_kernel, grid, block, 0, stream, img, out);
}